// Round 10
// baseline (564.387 us; speedup 1.0000x reference)
//
#include <hip/hip_runtime.h>
#include <hip/hip_bf16.h>
#include <math.h>

#define HIDDEN 512
#define ATTEN  512
#define BATCH  32
#define STEP   2048

#define BM 64                 // rows per scores block
#define BN 512                // full atten width (no N-slicing)
#define BK 32                 // K tile
#define NT (HIDDEN / BK)      // 16 K-tiles
#define THREADS 512           // 8 waves, wave tile 64 rows x 64 cols

#define NCH 16                // s-chunks in weighted-sum kernel
#define CHS (STEP / NCH)

typedef __attribute__((ext_vector_type(8))) short bf16x8;
typedef __attribute__((ext_vector_type(4))) short bf16x4;
typedef __attribute__((ext_vector_type(4))) float f32x4;

// batch_lens may arrive as int64 (reference dtype) or int32 (jax without x64).
// Values >= 1, so int32-view index 1 == 0 iff the buffer is int64.
__device__ __forceinline__ long long load_len(const int* lens_raw, int b) {
    bool is64 = (lens_raw[1] == 0);
    if (is64) return ((const long long*)lens_raw)[b];
    return (long long)lens_raw[b];
}

__device__ __forceinline__ short f2bf(float x) {        // RNE fp32 -> bf16 bits
    unsigned u = __float_as_uint(x);
    unsigned r = (u + 0x7FFFu + ((u >> 16) & 1u)) >> 16;
    return (short)r;
}
__device__ __forceinline__ float bf2f(short s) {
    return __uint_as_float(((unsigned)(unsigned short)s) << 16);
}

__device__ __forceinline__ float fast_tanh(float x) {
    float e = __expf(2.0f * x);         // saturates correctly at +-inf
    return 1.0f - 2.0f / (e + 1.0f);
}

// K0: pre-swizzled bf16-HI-only W (proven R9 pair-swizzle layout, BN=512).
// Per K-tile kt (16 KB... here 32 KB): col-pair r2=a>>1 owns a 128B LDS row
// = 8 slots of 16B; slot8 = ((a&1)*4 + s) ^ (r2&7), s = k-subslot (8 bf16).
// global chunk order n = r2*8 + slot8 (LDS byte = n*16).
// wglds[(kt*2048 + n)*8 + j], 512 KB total.
__global__ __launch_bounds__(512) void wsplit_kernel(
    const float* __restrict__ W, short* __restrict__ wglds)
{
    int a = blockIdx.x;       // 0..511  (atten col)
    int h = threadIdx.x;      // 0..511  (hidden = k)
    float v = W[(size_t)h * ATTEN + a];
    short hi = f2bf(v);
    int kt = h >> 5, s = (h >> 3) & 3, j = h & 7;
    int r2 = a >> 1;
    int slot8 = (((a & 1) << 2) | s) ^ (r2 & 7);
    wglds[((size_t)kt * 2048 + (size_t)r2 * 8 + slot8) * 8 + j] = hi;
}

// K1: scores over the FULL 512-col width. 64-row blocks, 8 waves, 40 KB LDS
// -> 4 blocks/CU = 1024 slots: all ~528 active blocks resident at once
// (kills the dispatch tail). Sync-only loop (R8/R9 proven), X prefetched
// 2 tiles ahead in registers, kt-staggered W reads.
__global__ __launch_bounds__(THREADS, 8) void scores_mfma_kernel(
    const float* __restrict__ X,        // [B*S*H] fp32
    const int*   __restrict__ lens_raw,
    const short* __restrict__ wglds,    // pre-swizzled bf16-hi W
    const float* __restrict__ bias,
    const float* __restrict__ ctx,
    float* __restrict__ scores)         // [B*S]
{
    __shared__ char smem[40 * 1024];
    char* const At = smem;              // 8 KB: X hi/lo, swizzled (64 x 128B)
    char* const Bt = smem + 8 * 1024;   // 32 KB: W hi, pair-swizzled

    const int tiles_per_b = STEP / BM;  // 32
    int mt = blockIdx.x;
    int b  = mt / tiles_per_b;
    int s0 = (mt % tiles_per_b) * BM;
    long long len = load_len(lens_raw, b);
    if ((long long)s0 >= len) return;   // softmax weight 0 for whole tile

    int ko = (mt * 7) & (NT - 1);       // per-block K-loop start (stagger)

    int t = threadIdx.x;
    int wave = t >> 6, lane = t & 63;
    int wcol = wave;                    // 8 N-waves x 64 cols, all 64 rows
    int l15 = lane & 15, l4 = lane >> 4;

    // A staging coords: thread -> (row ar, float4-index q within row)
    int ar = t >> 3, q = t & 7;
    const float* xrow = X + ((size_t)b * STEP + s0 + ar) * HIDDEN + q * 4;

    const short* wbase = wglds;
    int wvuni16 = (t & ~63) * 16;       // wave-uniform LDS byte base

    f32x4 acc[4][4];
#pragma unroll
    for (int mi = 0; mi < 4; ++mi)
#pragma unroll
        for (int ni = 0; ni < 4; ++ni)
            acc[mi][ni] = (f32x4){0.f, 0.f, 0.f, 0.f};

    float4 pxA, pxB;                    // X prefetch, 2 tiles ahead

// X load for tile KT -> register (1 float4/thread)
#define PXLOAD(KT, P)                                                        \
    do { P = *(const float4*)(xrow + (KT) * BK); } while (0)

// B-DMA for tile KT -> LDS (4 x global_load_lds 16B per thread = 32 KB)
#define BISSUE(KT)                                                           \
    do {                                                                     \
        _Pragma("unroll")                                                    \
        for (int i = 0; i < 4; ++i) {                                        \
            const short* g = wbase + ((size_t)(KT) * 2048 + i * 512 + t) * 8;\
            char* l = Bt + i * 8192 + wvuni16;                               \
            __builtin_amdgcn_global_load_lds(                                \
                (const __attribute__((address_space(1))) unsigned int*)g,    \
                (__attribute__((address_space(3))) unsigned int*)l,          \
                16, 0, 0);                                                   \
        }                                                                    \
    } while (0)

// convert one px float4 -> 4 hi + 4 lo bf16, swizzled 8B ds_writes into At
#define AWRITE(P)                                                            \
    do {                                                                     \
        float xs[4] = {P.x, P.y, P.z, P.w};                                  \
        bf16x4 hv, lv;                                                       \
        _Pragma("unroll")                                                    \
        for (int j = 0; j < 4; ++j) {                                        \
            short h_ = f2bf(xs[j]);                                          \
            hv[j] = h_;                                                      \
            lv[j] = f2bf(xs[j] - bf2f(h_));                                  \
        }                                                                    \
        int rx = ar & 7;                                                     \
        int s2 = q >> 1, hf = (q & 1) * 8;                                   \
        *(bf16x4*)(At + ar * 128 + (((s2) ^ rx) << 4) + hf) = hv;            \
        *(bf16x4*)(At + ar * 128 + (((4 + s2) ^ rx) << 4) + hf) = lv;        \
    } while (0)

// 2 terms: xh*wh + xl*wh (= x*wh exact; dropped x*wl ~ 2^-9 rel)
#define COMPUTE()                                                            \
    do {                                                                     \
        bf16x8 ah[4], al[4];                                                 \
        _Pragma("unroll")                                                    \
        for (int mi = 0; mi < 4; ++mi) {                                     \
            int row = mi * 16 + l15;                                         \
            int rx = row & 7;                                                \
            ah[mi] = *(const bf16x8*)(At + row * 128 + ((l4 ^ rx) << 4));    \
            al[mi] = *(const bf16x8*)(At + row * 128 + (((4 + l4) ^ rx) << 4)); \
        }                                                                    \
        _Pragma("unroll")                                                    \
        for (int ni = 0; ni < 4; ++ni) {                                     \
            int col = wcol * 64 + ni * 16 + l15;                             \
            int r2 = col >> 1;                                               \
            int sl = ((((col & 1) << 2) | l4) ^ (r2 & 7));                   \
            bf16x8 bh = *(const bf16x8*)(Bt + r2 * 128 + (sl << 4));         \
            _Pragma("unroll")                                                \
            for (int mi = 0; mi < 4; ++mi) {                                 \
                acc[mi][ni] = __builtin_amdgcn_mfma_f32_16x16x32_bf16(       \
                    ah[mi], bh, acc[mi][ni], 0, 0, 0);                       \
                acc[mi][ni] = __builtin_amdgcn_mfma_f32_16x16x32_bf16(       \
                    al[mi], bh, acc[mi][ni], 0, 0, 0);                       \
            }                                                                \
        }                                                                    \
    } while (0)

    // prologue: px(ko), px(ko+1) in flight; stage tile ko; full drain
    int k0 = ko, k1 = (ko + 1) & (NT - 1);
    PXLOAD(k0, pxA);
    PXLOAD(k1, pxB);
    BISSUE(k0);
    AWRITE(pxA);                        // compiler waits px(ko) only
    __syncthreads();                    // drains DMA + ds_writes

    int kcur = k0;
#pragma unroll
    for (int kt = 0; kt < NT; ++kt) {
        int knx2 = (kcur + 2) & (NT - 1);
        if (kt + 2 < NT) {              // px(kt+2) -> the set freed last phase
            if ((kt & 1) == 0) { PXLOAD(knx2, pxA); }
            else               { PXLOAD(knx2, pxB); }
        }
        COMPUTE();                      // tile kcur
        __syncthreads();                // all waves done reading At/Bt
        if (kt + 1 < NT) {
            int knxt = (kcur + 1) & (NT - 1);
            BISSUE(knxt);               // B-DMA (L2-resident W)
            if ((kt & 1) == 0) { AWRITE(pxB); }   // px(kt+1)
            else               { AWRITE(pxA); }
            __syncthreads();            // full drain: tiles ready
            kcur = knxt;
        }
    }
#undef PXLOAD
#undef BISSUE
#undef AWRITE
#undef COMPUTE

    // fused epilogue: tanh(acc+bias)*ctx reduced over all 512 cols
    float bi[4], ci[4];
#pragma unroll
    for (int ni = 0; ni < 4; ++ni) {
        int a = wcol * 64 + ni * 16 + l15;
        bi[ni] = bias[a];
        ci[ni] = ctx[a];
    }
    __syncthreads();                     // everyone done with LDS tiles
    float* partial = (float*)At;         // [8 wcol][BM]
#pragma unroll
    for (int mi = 0; mi < 4; ++mi) {
#pragma unroll
        for (int reg = 0; reg < 4; ++reg) {
            float s = 0.f;
#pragma unroll
            for (int ni = 0; ni < 4; ++ni)
                s += fast_tanh(acc[mi][ni][reg] + bi[ni]) * ci[ni];
            s += __shfl_xor(s, 1);
            s += __shfl_xor(s, 2);
            s += __shfl_xor(s, 4);
            s += __shfl_xor(s, 8);
            if (l15 == 0) {
                int row = mi * 16 + l4 * 4 + reg;   // C/D: row=(l>>4)*4+reg
                partial[wcol * BM + row] = s;
            }
        }
    }
    __syncthreads();
    if (t < BM) {
        float v = 0.f;
#pragma unroll
        for (int w = 0; w < 8; ++w) v += partial[w * BM + t];
        scores[(size_t)b * STEP + s0 + t] = v;
    }
}

// K2: masked softmax per batch row; atten aliases scores buffer
// (each element is read and written by the same thread).
__global__ __launch_bounds__(256) void softmax_kernel(
    const float* __restrict__ scores, const int* __restrict__ lens_raw,
    float* __restrict__ atten)
{
    __shared__ float wmax[4], wsum[4];
    int b = blockIdx.x;
    long long len = load_len(lens_raw, b);
    int t = threadIdx.x;
    const float* srow = scores + (size_t)b * STEP;
    float* arow = atten + (size_t)b * STEP;

    float sv[STEP / 256];
    float locmax = -INFINITY;
#pragma unroll
    for (int k = 0; k < 8; ++k) {
        int s = t + k * 256;
        float v = ((long long)s < len) ? srow[s] : -INFINITY;
        sv[k] = v;
        locmax = fmaxf(locmax, v);
    }
    for (int o = 1; o < 64; o <<= 1) locmax = fmaxf(locmax, __shfl_xor(locmax, o));
    int wave = t >> 6, lane = t & 63;
    if (lane == 0) wmax[wave] = locmax;
    __syncthreads();
    float gmax = fmaxf(fmaxf(wmax[0], wmax[1]), fmaxf(wmax[2], wmax[3]));

    float ev[8];
    float locsum = 0.f;
#pragma unroll
    for (int k = 0; k < 8; ++k) {
        float e = (sv[k] == -INFINITY) ? 0.f : expf(sv[k] - gmax);
        ev[k] = e;
        locsum += e;
    }
    for (int o = 1; o < 64; o <<= 1) locsum += __shfl_xor(locsum, o);
    if (lane == 0) wsum[wave] = locsum;
    __syncthreads();
    float inv = 1.f / (wsum[0] + wsum[1] + wsum[2] + wsum[3]);
#pragma unroll
    for (int k = 0; k < 8; ++k) {
        int s = t + k * 256;
        arow[s] = ev[k] * inv;
    }
}

// K3a: partial[b,ch,h] = sum_{s in chunk, s<len} atten[b,s] * X[b,s,h]
__global__ __launch_bounds__(256) void wsum_kernel(
    const float* __restrict__ X, const int* __restrict__ lens_raw,
    const float* __restrict__ atten, float* __restrict__ partial)
{
    int ch = blockIdx.x;
    int b  = blockIdx.y;
    long long len = load_len(lens_raw, b);
    int t = threadIdx.x;
    int s0 = ch * CHS;
    long long send_ll = (long long)(s0 + CHS);
    if (send_ll > len) send_ll = len;
    int send = (int)send_ll;

    const float* arow = atten + (size_t)b * STEP;
    float2 acc = {0.f, 0.f};
    for (int s = s0; s < send; ++s) {
        float a = arow[s];
        float2 xv = *(const float2*)(X + ((size_t)b * STEP + s) * HIDDEN + 2 * t);
        acc.x = fmaf(a, xv.x, acc.x);
        acc.y = fmaf(a, xv.y, acc.y);
    }
    float* prow = partial + ((size_t)b * NCH + ch) * HIDDEN;
    *(float2*)(prow + 2 * t) = acc;      // skipped chunks write zeros
}

// K3b: out[b,h] = sum_ch partial[b,ch,h]
__global__ __launch_bounds__(256) void finalize_kernel(
    const float* __restrict__ partial, float* __restrict__ out)
{
    int b = blockIdx.x;
    int t = threadIdx.x;
    float2 a = {0.f, 0.f};
#pragma unroll
    for (int ch = 0; ch < NCH; ++ch) {
        const float* prow = partial + ((size_t)b * NCH + ch) * HIDDEN;
        float2 v = *(const float2*)(prow + 2 * t);
        a.x += v.x;
        a.y += v.y;
    }
    *(float2*)(out + (size_t)b * HIDDEN + 2 * t) = a;
}

extern "C" void kernel_launch(void* const* d_in, const int* in_sizes, int n_in,
                              void* d_out, int out_size, void* d_ws, size_t ws_size,
                              hipStream_t stream) {
    const float* X    = (const float*)d_in[0];
    const int*   lens = (const int*)d_in[1];   // dtype sniffed on device
    const float* W    = (const float*)d_in[2];
    const float* bias = (const float*)d_in[3];
    const float* ctx  = (const float*)d_in[4];
    float* out = (float*)d_out;

    char* ws = (char*)d_ws;
    float* sp      = (float*)ws;                    // [B*S] = 256 KB
    float* atten   = sp;                            // aliases scores (safe)
    float* partial = (float*)(ws + 512 * 1024);     // 1 MB
    short* wglds   = (short*)(ws + 1536 * 1024);    // 512 KB pre-swizzled W-hi

    wsplit_kernel<<<dim3(ATTEN), 512, 0, stream>>>(W, wglds);
    scores_mfma_kernel<<<dim3(BATCH * (STEP / BM)), THREADS, 0, stream>>>(
        X, lens, wglds, bias, ctx, sp);
    softmax_kernel<<<dim3(BATCH), 256, 0, stream>>>(sp, lens, atten);
    wsum_kernel<<<dim3(NCH, BATCH), 256, 0, stream>>>(X, lens, atten, partial);
    finalize_kernel<<<dim3(BATCH), 256, 0, stream>>>(partial, out);
}

// Round 11
// 274.282 us; speedup vs baseline: 2.0577x; 2.0577x over previous
//
#include <hip/hip_runtime.h>
#include <hip/hip_bf16.h>
#include <math.h>

#define HIDDEN 512
#define ATTEN  512
#define BATCH  32
#define STEP   2048

#define BM 128                // rows per tile
#define BN 256                // atten cols per tile (2 N-slices)
#define NS (ATTEN / BN)       // 2
#define BK 32                 // K tile
#define NT (HIDDEN / BK)      // 16 K-tiles
#define THREADS 512           // 8 waves: 2(M) x 4(N), wave tile 64x64
#define NTILES (BATCH * (STEP / BM) * NS)   // 1024 work items

#define NCH 16                // s-chunks in weighted-sum kernel
#define CHS (STEP / NCH)

typedef __attribute__((ext_vector_type(8))) short bf16x8;
typedef __attribute__((ext_vector_type(4))) float f32x4;

// batch_lens may arrive as int64 (reference dtype) or int32 (jax without x64).
// Values >= 1, so int32-view index 1 == 0 iff the buffer is int64.
__device__ __forceinline__ long long load_len(const int* lens_raw, int b) {
    bool is64 = (lens_raw[1] == 0);
    if (is64) return ((const long long*)lens_raw)[b];
    return (long long)lens_raw[b];
}

__device__ __forceinline__ short f2bf(float x) {        // RNE fp32 -> bf16 bits
    unsigned u = __float_as_uint(x);
    unsigned r = (u + 0x7FFFu + ((u >> 16) & 1u)) >> 16;
    return (short)r;
}
__device__ __forceinline__ float bf2f(short s) {
    return __uint_as_float(((unsigned)(unsigned short)s) << 16);
}

__device__ __forceinline__ float fast_tanh(float x) {
    float e = __expf(2.0f * x);         // saturates correctly at +-inf
    return 1.0f - 2.0f / (e + 1.0f);
}

// K0: pre-swizzled bf16-HI-only W (R9-proven layout) + work-counter reset.
// Per N-slice ns, K-tile kt: col-pair r2=c>>1 owns a 128B LDS row = 8 slots
// of 16B; slot8 = ((c&1)*4 + s) ^ (r2&7). global chunk n = r2*8 + slot8.
// wglds[((ns*16+kt)*1024 + n)*8 + j], 512 KB total.
__global__ __launch_bounds__(512) void wsplit_kernel(
    const float* __restrict__ W, short* __restrict__ wglds, int* __restrict__ ctr)
{
    if (blockIdx.x == 0 && threadIdx.x == 0) *ctr = 0;   // reset work queue
    int a = blockIdx.x;       // 0..511  (atten col)
    int h = threadIdx.x;      // 0..511  (hidden = k)
    float v = W[(size_t)h * ATTEN + a];
    short hi = f2bf(v);
    int ns = a >> 8, c = a & 255;
    int kt = h >> 5, s = (h >> 3) & 3, j = h & 7;
    int r2 = c >> 1;
    int slot8 = (((c & 1) << 2) | s) ^ (r2 & 7);
    size_t tb = ((size_t)ns * NT + kt) * 1024;
    wglds[(tb + (size_t)r2 * 8 + slot8) * 8 + j] = hi;
}

// K1: persistent-block scores. 512 blocks (2/CU, all resident), each grabs
// tiles from an atomic queue. Per tile: R6's verified counted-vmcnt pipeline
// (A 2-buf, B 3-buf, loads issued 2 phases ahead, vmcnt(4) steady state).
__global__ __launch_bounds__(THREADS, 4) void scores_mfma_kernel(
    const float* __restrict__ X,        // [B*S*H] fp32
    const int*   __restrict__ lens_raw,
    const short* __restrict__ wglds,    // pre-swizzled bf16-hi W
    const float* __restrict__ bias,
    const float* __restrict__ ctx,
    float* __restrict__ scores_part,    // [NS][B*S]
    int* __restrict__ ctr)
{
    extern __shared__ char smem[];      // 80 KB dynamic
    char* const A0 = smem;              // 16 KB each
    char* const A1 = smem + 16 * 1024;
    char* const Bb0 = smem + 32 * 1024;
    char* const Bb1 = smem + 48 * 1024;
    char* const Bb2 = smem + 64 * 1024;
    char* const smAarr[2] = {A0, A1};
    char* const smBarr[3] = {Bb0, Bb1, Bb2};
    __shared__ int widx;

    int t = threadIdx.x;
    int wave = t >> 6, lane = t & 63;
    int wrow = wave >> 2, wcol = wave & 3;      // 2 x 4 wave grid
    int l15 = lane & 15, l4 = lane >> 4;
    int ar = t >> 2, aq = t & 3;                // A staging: row, k-subslot
    int wvuni16 = (t & ~63) * 16;               // wave-uniform LDS byte base

    // bias/ctx per wave column slice (same for every tile's ns? no - ns varies;
    // loaded per tile below)

    for (;;) {
        __syncthreads();                 // guards widx + LDS reuse across tiles
        if (t == 0) widx = atomicAdd(ctr, 1);
        __syncthreads();
        int idx = widx;
        if (idx >= NTILES) break;

        int ns = idx & 1;                // ns fastest: consecutive grabs share X
        int mt = idx >> 1;
        int b  = mt >> 4;                // 16 tiles per batch (BM=128)
        int s0 = (mt & 15) * BM;
        long long len = load_len(lens_raw, b);
        if ((long long)s0 >= len) continue;

        int ko = (idx * 7) & (NT - 1);   // K-loop stagger

        const float* xrow = X + ((size_t)b * STEP + s0 + ar) * HIDDEN + aq * 8;
        const short* wbase = wglds + (size_t)ns * NT * 1024 * 8;

        f32x4 acc[4][4];
#pragma unroll
        for (int mi = 0; mi < 4; ++mi)
#pragma unroll
            for (int ni = 0; ni < 4; ++ni)
                acc[mi][ni] = (f32x4){0.f, 0.f, 0.f, 0.f};

        float4 pxA0, pxA1, pxB0, pxB1;   // px sets: even/odd loop phase

#define PXLOAD(KG, P0, P1)                                                   \
    do {                                                                     \
        P0 = *(const float4*)(xrow + (KG) * BK);                             \
        P1 = *(const float4*)(xrow + (KG) * BK + 4);                         \
    } while (0)

#define BISSUE(KG, SB)                                                       \
    do {                                                                     \
        _Pragma("unroll")                                                    \
        for (int i = 0; i < 2; ++i) {                                        \
            const short* g = wbase + ((size_t)(KG) * 1024 + i * 512 + t) * 8;\
            char* l = (SB) + i * 512 * 16 + wvuni16;                         \
            __builtin_amdgcn_global_load_lds(                                \
                (const __attribute__((address_space(1))) unsigned int*)g,    \
                (__attribute__((address_space(3))) unsigned int*)l,          \
                16, 0, 0);                                                   \
        }                                                                    \
    } while (0)

#define AWRITE(P0, P1, SA)                                                   \
    do {                                                                     \
        float xs[8] = {P0.x, P0.y, P0.z, P0.w, P1.x, P1.y, P1.z, P1.w};      \
        bf16x8 hv, lv;                                                       \
        _Pragma("unroll")                                                    \
        for (int j = 0; j < 8; ++j) {                                        \
            short h_ = f2bf(xs[j]);                                          \
            hv[j] = h_;                                                      \
            lv[j] = f2bf(xs[j] - bf2f(h_));                                  \
        }                                                                    \
        int rx = ar & 7;                                                     \
        *(bf16x8*)((SA) + ar * 128 + (((aq) ^ rx) << 4)) = hv;               \
        *(bf16x8*)((SA) + ar * 128 + (((4 + aq) ^ rx) << 4)) = lv;           \
    } while (0)

// 2 terms: xh*wh + xl*wh (= x*wh exact; dropped x*wl ~ 2^-9 rel)
#define COMPUTE(SA, SB)                                                      \
    do {                                                                     \
        bf16x8 ah[4], al[4];                                                 \
        _Pragma("unroll")                                                    \
        for (int mi = 0; mi < 4; ++mi) {                                     \
            int row = wrow * 64 + mi * 16 + l15;                             \
            int rx = row & 7;                                                \
            ah[mi] = *(const bf16x8*)((SA) + row * 128 + ((l4 ^ rx) << 4));  \
            al[mi] = *(const bf16x8*)((SA) + row * 128 + (((4 + l4) ^ rx) << 4)); \
        }                                                                    \
        _Pragma("unroll")                                                    \
        for (int ni = 0; ni < 4; ++ni) {                                     \
            int col = wcol * 64 + ni * 16 + l15;                             \
            int r2 = col >> 1;                                               \
            int sl = ((((col & 1) << 2) | l4) ^ (r2 & 7));                   \
            bf16x8 bh = *(const bf16x8*)((SB) + r2 * 128 + (sl << 4));       \
            _Pragma("unroll")                                                \
            for (int mi = 0; mi < 4; ++mi) {                                 \
                acc[mi][ni] = __builtin_amdgcn_mfma_f32_16x16x32_bf16(       \
                    ah[mi], bh, acc[mi][ni], 0, 0, 0);                       \
                acc[mi][ni] = __builtin_amdgcn_mfma_f32_16x16x32_bf16(       \
                    al[mi], bh, acc[mi][ni], 0, 0, 0);                       \
            }                                                                \
        }                                                                    \
    } while (0)

        // prologue (R6 schedule): tiles ko, ko+1 in flight
        int g0 = ko, g1 = (ko + 1) & (NT - 1);
        BISSUE(g0, Bb0);
        PXLOAD(g0, pxA0, pxA1);
        BISSUE(g1, Bb1);
        PXLOAD(g1, pxB0, pxB1);
        AWRITE(pxA0, pxA1, A0);          // implicit wait retires B(g0),px(g0)
        asm volatile("s_waitcnt lgkmcnt(0)" ::: "memory");
        asm volatile("s_waitcnt vmcnt(4)" ::: "memory");  // B(g1),px(g1) fly
        __builtin_amdgcn_s_barrier();
        __builtin_amdgcn_sched_barrier(0);

#pragma unroll
        for (int kt = 0; kt < NT; ++kt) {
            int kg2 = (ko + kt + 2) & (NT - 1);
            if (kt + 2 < NT) {
                BISSUE(kg2, smBarr[(kt + 2) % 3]);   // buf read-retired @ kt-1
                if ((kt & 1) == 0) { PXLOAD(kg2, pxA0, pxA1); }
                else               { PXLOAD(kg2, pxB0, pxB1); }
            }
            COMPUTE(smAarr[kt & 1], smBarr[kt % 3]);
            if (kt + 1 < NT) {
                if ((kt & 1) == 0) { AWRITE(pxB0, pxB1, smAarr[(kt + 1) & 1]); }
                else               { AWRITE(pxA0, pxA1, smAarr[(kt + 1) & 1]); }
                asm volatile("s_waitcnt lgkmcnt(0)" ::: "memory");
                if (kt + 2 < NT) {
                    asm volatile("s_waitcnt vmcnt(4)" ::: "memory");
                } else {
                    asm volatile("s_waitcnt vmcnt(0)" ::: "memory");
                }
                __builtin_amdgcn_s_barrier();
                __builtin_amdgcn_sched_barrier(0);
            }
        }
#undef PXLOAD
#undef BISSUE
#undef AWRITE
#undef COMPUTE

        // fused epilogue: tanh(acc+bias)*ctx over this slice's 256 cols
        float bi[4], ci[4];
#pragma unroll
        for (int ni = 0; ni < 4; ++ni) {
            int a = ns * BN + wcol * 64 + ni * 16 + l15;
            bi[ni] = bias[a];
            ci[ni] = ctx[a];
        }
        __syncthreads();                 // all waves done with LDS tiles
        float* partial = (float*)A0;     // [4 wcol][BM]
#pragma unroll
        for (int mi = 0; mi < 4; ++mi) {
#pragma unroll
            for (int reg = 0; reg < 4; ++reg) {
                float s = 0.f;
#pragma unroll
                for (int ni = 0; ni < 4; ++ni)
                    s += fast_tanh(acc[mi][ni][reg] + bi[ni]) * ci[ni];
                s += __shfl_xor(s, 1);
                s += __shfl_xor(s, 2);
                s += __shfl_xor(s, 4);
                s += __shfl_xor(s, 8);
                if (l15 == 0) {
                    int row = wrow * 64 + mi * 16 + l4 * 4 + reg;  // C/D layout
                    partial[wcol * BM + row] = s;
                }
            }
        }
        __syncthreads();
        if (t < BM) {
            float v = partial[0 * BM + t] + partial[1 * BM + t]
                    + partial[2 * BM + t] + partial[3 * BM + t];
            scores_part[((size_t)ns * BATCH + b) * STEP + s0 + t] = v;
        }
    }
}

// K2: masked softmax; sums the 2 N-slice partials; atten aliases slice-0
// buffer (each element is read and written by the same thread).
__global__ __launch_bounds__(256) void softmax_kernel(
    const float* __restrict__ p0, const float* __restrict__ p1,
    const int* __restrict__ lens_raw, float* __restrict__ atten)
{
    __shared__ float wmax[4], wsum[4];
    int b = blockIdx.x;
    long long len = load_len(lens_raw, b);
    int t = threadIdx.x;
    const float* r0 = p0 + (size_t)b * STEP;
    const float* r1 = p1 + (size_t)b * STEP;
    float* arow = atten + (size_t)b * STEP;

    float sv[STEP / 256];
    float locmax = -INFINITY;
#pragma unroll
    for (int k = 0; k < 8; ++k) {
        int s = t + k * 256;
        float v = ((long long)s < len) ? (r0[s] + r1[s]) : -INFINITY;
        sv[k] = v;
        locmax = fmaxf(locmax, v);
    }
    for (int o = 1; o < 64; o <<= 1) locmax = fmaxf(locmax, __shfl_xor(locmax, o));
    int wave = t >> 6, lane = t & 63;
    if (lane == 0) wmax[wave] = locmax;
    __syncthreads();
    float gmax = fmaxf(fmaxf(wmax[0], wmax[1]), fmaxf(wmax[2], wmax[3]));

    float ev[8];
    float locsum = 0.f;
#pragma unroll
    for (int k = 0; k < 8; ++k) {
        float e = (sv[k] == -INFINITY) ? 0.f : expf(sv[k] - gmax);
        ev[k] = e;
        locsum += e;
    }
    for (int o = 1; o < 64; o <<= 1) locsum += __shfl_xor(locsum, o);
    if (lane == 0) wsum[wave] = locsum;
    __syncthreads();
    float inv = 1.f / (wsum[0] + wsum[1] + wsum[2] + wsum[3]);
#pragma unroll
    for (int k = 0; k < 8; ++k) {
        int s = t + k * 256;
        arow[s] = ev[k] * inv;
    }
}

// K3a: partial[b,ch,h] = sum_{s in chunk, s<len} atten[b,s] * X[b,s,h]
__global__ __launch_bounds__(256) void wsum_kernel(
    const float* __restrict__ X, const int* __restrict__ lens_raw,
    const float* __restrict__ atten, float* __restrict__ partial)
{
    int ch = blockIdx.x;
    int b  = blockIdx.y;
    long long len = load_len(lens_raw, b);
    int t = threadIdx.x;
    int s0 = ch * CHS;
    long long send_ll = (long long)(s0 + CHS);
    if (send_ll > len) send_ll = len;
    int send = (int)send_ll;

    const float* arow = atten + (size_t)b * STEP;
    float2 acc = {0.f, 0.f};
    for (int s = s0; s < send; ++s) {
        float a = arow[s];
        float2 xv = *(const float2*)(X + ((size_t)b * STEP + s) * HIDDEN + 2 * t);
        acc.x = fmaf(a, xv.x, acc.x);
        acc.y = fmaf(a, xv.y, acc.y);
    }
    float* prow = partial + ((size_t)b * NCH + ch) * HIDDEN;
    *(float2*)(prow + 2 * t) = acc;      // skipped chunks write zeros
}

// K3b: out[b,h] = sum_ch partial[b,ch,h]
__global__ __launch_bounds__(256) void finalize_kernel(
    const float* __restrict__ partial, float* __restrict__ out)
{
    int b = blockIdx.x;
    int t = threadIdx.x;
    float2 a = {0.f, 0.f};
#pragma unroll
    for (int ch = 0; ch < NCH; ++ch) {
        const float* prow = partial + ((size_t)b * NCH + ch) * HIDDEN;
        float2 v = *(const float2*)(prow + 2 * t);
        a.x += v.x;
        a.y += v.y;
    }
    *(float2*)(out + (size_t)b * HIDDEN + 2 * t) = a;
}

extern "C" void kernel_launch(void* const* d_in, const int* in_sizes, int n_in,
                              void* d_out, int out_size, void* d_ws, size_t ws_size,
                              hipStream_t stream) {
    const float* X    = (const float*)d_in[0];
    const int*   lens = (const int*)d_in[1];   // dtype sniffed on device
    const float* W    = (const float*)d_in[2];
    const float* bias = (const float*)d_in[3];
    const float* ctx  = (const float*)d_in[4];
    float* out = (float*)d_out;

    char* ws = (char*)d_ws;
    float* sp      = (float*)ws;                    // [2][B*S] = 512 KB
    float* atten   = sp;                            // aliases slice-0 (safe)
    float* partial = (float*)(ws + 512 * 1024);     // 1 MB
    short* wglds   = (short*)(ws + 1536 * 1024);    // 512 KB pre-swizzled W-hi
    int*   ctr     = (int*)(ws + 2048 * 1024);      // work-queue counter

    (void)hipFuncSetAttribute((const void*)scores_mfma_kernel,
                              hipFuncAttributeMaxDynamicSharedMemorySize,
                              80 * 1024);

    wsplit_kernel<<<dim3(ATTEN), 512, 0, stream>>>(W, wglds, ctr);
    scores_mfma_kernel<<<dim3(512), THREADS, 80 * 1024, stream>>>(
        X, lens, wglds, bias, ctx, sp, ctr);
    softmax_kernel<<<dim3(BATCH), 256, 0, stream>>>(
        sp, sp + (size_t)BATCH * STEP, lens, atten);
    wsum_kernel<<<dim3(NCH, BATCH), 256, 0, stream>>>(X, lens, atten, partial);
    finalize_kernel<<<dim3(BATCH), 256, 0, stream>>>(partial, out);
}

// Round 12
// 122.174 us; speedup vs baseline: 4.6195x; 2.2450x over previous
//
#include <hip/hip_runtime.h>
#include <hip/hip_bf16.h>
#include <math.h>

#define HIDDEN 512
#define ATTEN  512
#define BATCH  32
#define STEP   2048

#define BM 128                // rows per tile
#define BN 256                // atten cols per tile (2 N-slices)
#define NS (ATTEN / BN)       // 2
#define BK 32                 // K tile
#define NT (HIDDEN / BK)      // 16 K-tiles
#define THREADS 512           // 8 waves: 2(M) x 4(N), wave tile 64x64
#define NTILES (BATCH * (STEP / BM) * NS)   // 1024 work items
#define NBLOCKS 512           // persistent blocks: 2/CU, all resident

#define NCH 16                // s-chunks in weighted-sum kernel
#define CHS (STEP / NCH)

typedef __attribute__((ext_vector_type(8))) short bf16x8;
typedef __attribute__((ext_vector_type(4))) float f32x4;

// batch_lens may arrive as int64 (reference dtype) or int32 (jax without x64).
// Values >= 1, so int32-view index 1 == 0 iff the buffer is int64.
__device__ __forceinline__ long long load_len(const int* lens_raw, int b) {
    bool is64 = (lens_raw[1] == 0);
    if (is64) return ((const long long*)lens_raw)[b];
    return (long long)lens_raw[b];
}

__device__ __forceinline__ short f2bf(float x) {        // RNE fp32 -> bf16 bits
    unsigned u = __float_as_uint(x);
    unsigned r = (u + 0x7FFFu + ((u >> 16) & 1u)) >> 16;
    return (short)r;
}
__device__ __forceinline__ float bf2f(short s) {
    return __uint_as_float(((unsigned)(unsigned short)s) << 16);
}

__device__ __forceinline__ float fast_tanh(float x) {
    float e = __expf(2.0f * x);         // saturates correctly at +-inf
    return 1.0f - 2.0f / (e + 1.0f);
}

// K0: pre-swizzled bf16-HI-only W (R9-proven layout) + work-counter reset.
// Per N-slice ns, K-tile kt: col-pair r2=c>>1 owns a 128B LDS row = 8 slots
// of 16B; slot8 = ((c&1)*4 + s) ^ (r2&7). global chunk n = r2*8 + slot8.
// wglds[((ns*16+kt)*1024 + n)*8 + j], 512 KB total.
__global__ __launch_bounds__(512) void wsplit_kernel(
    const float* __restrict__ W, short* __restrict__ wglds, int* __restrict__ ctr)
{
    if (blockIdx.x == 0 && threadIdx.x == 0) *ctr = 0;   // reset work queue
    int a = blockIdx.x;       // 0..511  (atten col)
    int h = threadIdx.x;      // 0..511  (hidden = k)
    float v = W[(size_t)h * ATTEN + a];
    short hi = f2bf(v);
    int ns = a >> 8, c = a & 255;
    int kt = h >> 5, s = (h >> 3) & 3, j = h & 7;
    int r2 = c >> 1;
    int slot8 = (((c & 1) << 2) | s) ^ (r2 & 7);
    size_t tb = ((size_t)ns * NT + kt) * 1024;
    wglds[(tb + (size_t)r2 * 8 + slot8) * 8 + j] = hi;
}

// K1: persistent-block scores. 512 blocks (2/CU), atomic work queue for
// load balance. Per tile: R9's PROVEN 64-VGPR sync-only body verbatim
// (A+B single-buffered, __syncthreads-only waits, X prefetch 1 ahead).
__global__ __launch_bounds__(THREADS, 4) void scores_mfma_kernel(
    const float* __restrict__ X,        // [B*S*H] fp32
    const int*   __restrict__ lens_raw,
    const short* __restrict__ wglds,    // pre-swizzled bf16-hi W
    const float* __restrict__ bias,
    const float* __restrict__ ctx,
    float* __restrict__ scores_part,    // [NS][B*S]
    int* __restrict__ ctr)
{
    __shared__ char smem[32 * 1024];
    char* const At = smem;              // 16 KB: X hi/lo, swizzled
    char* const Bt = smem + 16 * 1024;  // 16 KB: W hi, pair-swizzled
    __shared__ int widx;

    int t = threadIdx.x;
    int wave = t >> 6, lane = t & 63;
    int wrow = wave >> 2, wcol = wave & 3;      // 2 x 4 wave grid
    int l15 = lane & 15, l4 = lane >> 4;
    int ar = t >> 2, aq = t & 3;                // A staging: row, k-subslot
    int wvuni16 = (t & ~63) * 16;               // wave-uniform LDS byte base

    for (;;) {
        __syncthreads();                 // guards widx + LDS reuse across tiles
        if (t == 0) widx = atomicAdd(ctr, 1);
        __syncthreads();
        int idx = widx;
        if (idx >= NTILES) break;

        int ns = idx & 1;                // ns fastest: consecutive grabs share X
        int mt = idx >> 1;
        int b  = mt >> 4;                // 16 tiles per batch (BM=128)
        int s0 = (mt & 15) * BM;
        long long len = load_len(lens_raw, b);
        if ((long long)s0 >= len) continue;

        int ko = (idx * 7) & (NT - 1);   // K-loop stagger (sum order-free)

        const float* xrow = X + ((size_t)b * STEP + s0 + ar) * HIDDEN + aq * 8;
        const short* wbase = wglds + (size_t)ns * NT * 1024 * 8;

        f32x4 acc[4][4];
#pragma unroll
        for (int mi = 0; mi < 4; ++mi)
#pragma unroll
            for (int ni = 0; ni < 4; ++ni)
                acc[mi][ni] = (f32x4){0.f, 0.f, 0.f, 0.f};

        float4 px0, px1;                 // X prefetch (one tile ahead)

#define PXLOAD(KG)                                                           \
    do {                                                                     \
        px0 = *(const float4*)(xrow + (KG) * BK);                            \
        px1 = *(const float4*)(xrow + (KG) * BK + 4);                        \
    } while (0)

#define BISSUE(KG)                                                           \
    do {                                                                     \
        _Pragma("unroll")                                                    \
        for (int i = 0; i < 2; ++i) {                                        \
            const short* g = wbase + ((size_t)(KG) * 1024 + i * 512 + t) * 8;\
            char* l = Bt + i * 512 * 16 + wvuni16;                           \
            __builtin_amdgcn_global_load_lds(                                \
                (const __attribute__((address_space(1))) unsigned int*)g,    \
                (__attribute__((address_space(3))) unsigned int*)l,          \
                16, 0, 0);                                                   \
        }                                                                    \
    } while (0)

#define AWRITE()                                                             \
    do {                                                                     \
        float xs[8] = {px0.x, px0.y, px0.z, px0.w, px1.x, px1.y, px1.z, px1.w};\
        bf16x8 hv, lv;                                                       \
        _Pragma("unroll")                                                    \
        for (int j = 0; j < 8; ++j) {                                        \
            short h_ = f2bf(xs[j]);                                          \
            hv[j] = h_;                                                      \
            lv[j] = f2bf(xs[j] - bf2f(h_));                                  \
        }                                                                    \
        int rx = ar & 7;                                                     \
        *(bf16x8*)(At + ar * 128 + (((aq) ^ rx) << 4)) = hv;                 \
        *(bf16x8*)(At + ar * 128 + (((4 + aq) ^ rx) << 4)) = lv;             \
    } while (0)

// 2 terms: xh*wh + xl*wh (= x*wh exact; dropped x*wl ~ 2^-9 rel)
#define COMPUTE()                                                            \
    do {                                                                     \
        bf16x8 ah[4], al[4];                                                 \
        _Pragma("unroll")                                                    \
        for (int mi = 0; mi < 4; ++mi) {                                     \
            int row = wrow * 64 + mi * 16 + l15;                             \
            int rx = row & 7;                                                \
            ah[mi] = *(const bf16x8*)(At + row * 128 + ((l4 ^ rx) << 4));    \
            al[mi] = *(const bf16x8*)(At + row * 128 + (((4 + l4) ^ rx) << 4)); \
        }                                                                    \
        _Pragma("unroll")                                                    \
        for (int ni = 0; ni < 4; ++ni) {                                     \
            int col = wcol * 64 + ni * 16 + l15;                             \
            int r2 = col >> 1;                                               \
            int sl = ((((col & 1) << 2) | l4) ^ (r2 & 7));                   \
            bf16x8 bh = *(const bf16x8*)(Bt + r2 * 128 + (sl << 4));         \
            _Pragma("unroll")                                                \
            for (int mi = 0; mi < 4; ++mi) {                                 \
                acc[mi][ni] = __builtin_amdgcn_mfma_f32_16x16x32_bf16(       \
                    ah[mi], bh, acc[mi][ni], 0, 0, 0);                       \
                acc[mi][ni] = __builtin_amdgcn_mfma_f32_16x16x32_bf16(       \
                    al[mi], bh, acc[mi][ni], 0, 0, 0);                       \
            }                                                                \
        }                                                                    \
    } while (0)

        // prologue: stage tile ko (X conv + B-DMA), full drain (R9 verbatim)
        int kcur = ko;
        PXLOAD(kcur);
        BISSUE(kcur);
        AWRITE();                        // compiler waits px vmcnt
        __syncthreads();                 // drains DMA + ds_writes

#pragma unroll
        for (int kt = 0; kt < NT; ++kt) {
            int knxt = (kcur + 1) & (NT - 1);
            if (kt + 1 < NT) PXLOAD(knxt);   // X(next) flies under COMPUTE
            COMPUTE();
            __syncthreads();                 // all waves done reading At/Bt
            if (kt + 1 < NT) {
                BISSUE(knxt);                // B-DMA (L2-resident W)
                AWRITE();                    // convert px(next) while DMA flies
                __syncthreads();             // full drain: tiles ready
            }
            kcur = knxt;
        }
#undef PXLOAD
#undef BISSUE
#undef AWRITE
#undef COMPUTE

        // fused epilogue: tanh(acc+bias)*ctx over this slice's 256 cols
        float bi[4], ci[4];
#pragma unroll
        for (int ni = 0; ni < 4; ++ni) {
            int a = ns * BN + wcol * 64 + ni * 16 + l15;
            bi[ni] = bias[a];
            ci[ni] = ctx[a];
        }
        __syncthreads();                 // all waves done with LDS tiles
        float* partial = (float*)At;     // [4 wcol][BM]
#pragma unroll
        for (int mi = 0; mi < 4; ++mi) {
#pragma unroll
            for (int reg = 0; reg < 4; ++reg) {
                float s = 0.f;
#pragma unroll
                for (int ni = 0; ni < 4; ++ni)
                    s += fast_tanh(acc[mi][ni][reg] + bi[ni]) * ci[ni];
                s += __shfl_xor(s, 1);
                s += __shfl_xor(s, 2);
                s += __shfl_xor(s, 4);
                s += __shfl_xor(s, 8);
                if (l15 == 0) {
                    int row = wrow * 64 + mi * 16 + l4 * 4 + reg;  // C/D layout
                    partial[wcol * BM + row] = s;
                }
            }
        }
        __syncthreads();
        if (t < BM) {
            float v = partial[0 * BM + t] + partial[1 * BM + t]
                    + partial[2 * BM + t] + partial[3 * BM + t];
            scores_part[((size_t)ns * BATCH + b) * STEP + s0 + t] = v;
        }
    }
}

// K2: masked softmax; sums the 2 N-slice partials; atten aliases slice-0
// buffer (each element is read and written by the same thread).
__global__ __launch_bounds__(256) void softmax_kernel(
    const float* __restrict__ p0, const float* __restrict__ p1,
    const int* __restrict__ lens_raw, float* __restrict__ atten)
{
    __shared__ float wmax[4], wsum[4];
    int b = blockIdx.x;
    long long len = load_len(lens_raw, b);
    int t = threadIdx.x;
    const float* r0 = p0 + (size_t)b * STEP;
    const float* r1 = p1 + (size_t)b * STEP;
    float* arow = atten + (size_t)b * STEP;

    float sv[STEP / 256];
    float locmax = -INFINITY;
#pragma unroll
    for (int k = 0; k < 8; ++k) {
        int s = t + k * 256;
        float v = ((long long)s < len) ? (r0[s] + r1[s]) : -INFINITY;
        sv[k] = v;
        locmax = fmaxf(locmax, v);
    }
    for (int o = 1; o < 64; o <<= 1) locmax = fmaxf(locmax, __shfl_xor(locmax, o));
    int wave = t >> 6, lane = t & 63;
    if (lane == 0) wmax[wave] = locmax;
    __syncthreads();
    float gmax = fmaxf(fmaxf(wmax[0], wmax[1]), fmaxf(wmax[2], wmax[3]));

    float ev[8];
    float locsum = 0.f;
#pragma unroll
    for (int k = 0; k < 8; ++k) {
        float e = (sv[k] == -INFINITY) ? 0.f : expf(sv[k] - gmax);
        ev[k] = e;
        locsum += e;
    }
    for (int o = 1; o < 64; o <<= 1) locsum += __shfl_xor(locsum, o);
    if (lane == 0) wsum[wave] = locsum;
    __syncthreads();
    float inv = 1.f / (wsum[0] + wsum[1] + wsum[2] + wsum[3]);
#pragma unroll
    for (int k = 0; k < 8; ++k) {
        int s = t + k * 256;
        arow[s] = ev[k] * inv;
    }
}

// K3a: partial[b,ch,h] = sum_{s in chunk, s<len} atten[b,s] * X[b,s,h]
__global__ __launch_bounds__(256) void wsum_kernel(
    const float* __restrict__ X, const int* __restrict__ lens_raw,
    const float* __restrict__ atten, float* __restrict__ partial)
{
    int ch = blockIdx.x;
    int b  = blockIdx.y;
    long long len = load_len(lens_raw, b);
    int t = threadIdx.x;
    int s0 = ch * CHS;
    long long send_ll = (long long)(s0 + CHS);
    if (send_ll > len) send_ll = len;
    int send = (int)send_ll;

    const float* arow = atten + (size_t)b * STEP;
    float2 acc = {0.f, 0.f};
    for (int s = s0; s < send; ++s) {
        float a = arow[s];
        float2 xv = *(const float2*)(X + ((size_t)b * STEP + s) * HIDDEN + 2 * t);
        acc.x = fmaf(a, xv.x, acc.x);
        acc.y = fmaf(a, xv.y, acc.y);
    }
    float* prow = partial + ((size_t)b * NCH + ch) * HIDDEN;
    *(float2*)(prow + 2 * t) = acc;      // skipped chunks write zeros
}

// K3b: out[b,h] = sum_ch partial[b,ch,h]
__global__ __launch_bounds__(256) void finalize_kernel(
    const float* __restrict__ partial, float* __restrict__ out)
{
    int b = blockIdx.x;
    int t = threadIdx.x;
    float2 a = {0.f, 0.f};
#pragma unroll
    for (int ch = 0; ch < NCH; ++ch) {
        const float* prow = partial + ((size_t)b * NCH + ch) * HIDDEN;
        float2 v = *(const float2*)(prow + 2 * t);
        a.x += v.x;
        a.y += v.y;
    }
    *(float2*)(out + (size_t)b * HIDDEN + 2 * t) = a;
}

extern "C" void kernel_launch(void* const* d_in, const int* in_sizes, int n_in,
                              void* d_out, int out_size, void* d_ws, size_t ws_size,
                              hipStream_t stream) {
    const float* X    = (const float*)d_in[0];
    const int*   lens = (const int*)d_in[1];   // dtype sniffed on device
    const float* W    = (const float*)d_in[2];
    const float* bias = (const float*)d_in[3];
    const float* ctx  = (const float*)d_in[4];
    float* out = (float*)d_out;

    char* ws = (char*)d_ws;
    float* sp      = (float*)ws;                    // [2][B*S] = 512 KB
    float* atten   = sp;                            // aliases slice-0 (safe)
    float* partial = (float*)(ws + 512 * 1024);     // 1 MB
    short* wglds   = (short*)(ws + 1536 * 1024);    // 512 KB pre-swizzled W-hi
    int*   ctr     = (int*)(ws + 2048 * 1024);      // work-queue counter

    wsplit_kernel<<<dim3(ATTEN), 512, 0, stream>>>(W, wglds, ctr);
    scores_mfma_kernel<<<dim3(NBLOCKS), THREADS, 0, stream>>>(
        X, lens, wglds, bias, ctx, sp, ctr);
    softmax_kernel<<<dim3(BATCH), 256, 0, stream>>>(
        sp, sp + (size_t)BATCH * STEP, lens, atten);
    wsum_kernel<<<dim3(NCH, BATCH), 256, 0, stream>>>(X, lens, atten, partial);
    finalize_kernel<<<dim3(BATCH), 256, 0, stream>>>(partial, out);
}